// Round 1
// 36984.988 us; speedup vs baseline: 1.0424x; 1.0424x over previous
//
#include <hip/hip_runtime.h>
#include <stdint.h>

#define MDIM   1024
#define NGATE5 5120
#define TSTEPS 8192
#define NWG    64
#define NTHR   512

typedef unsigned int u32x4 __attribute__((ext_vector_type(4)));

__device__ __forceinline__ float sigmoidf_(float x) {
  return 1.f / (1.f + __expf(-x));
}
// Fast tanh: avoids OCML tanhf (~50+ inst) on the critical path. ~1e-6 abs err.
__device__ __forceinline__ float tanhf_(float x) {
  float ax = fminf(fabsf(x), 15.f);
  float e = __expf(2.f * ax);
  float t = 1.f - 2.f / (e + 1.f);
  return copysignf(t, x);
}

// One 16-B LLC-coherent load (bypasses L1/L2: per-XCD L2s are not coherent).
// Single load + single waitcnt = one fabric round trip per poll round.
// (R5: per-round buffer_inv + cacheable loads 3.8x WORSE. R4: two serialized
// vmcnt(0) loads per round doubled round latency -> 2 slots per dwordx4.)
__device__ __forceinline__ u32x4 load16_coherent(const unsigned long long* p) {
  u32x4 r;
  asm volatile("global_load_dwordx4 %0, %1, off sc0 sc1\n\t"
               "s_waitcnt vmcnt(0)"
               : "=&v"(r) : "v"(p) : "memory");
  return r;
}

// R6: packed dual-slot publish. Both (value,tag) u64 halves travel in ONE
// 16-B VMEM request to one LLC line -> halves publish request count vs two
// 8-B atomic stores; each 8-B half is self-consistent (val+tag together).
__device__ __forceinline__ void store16_coherent(unsigned long long* p,
                                                 float v0, float v1, unsigned tag) {
  u32x4 d;
  d.x = __float_as_uint(v0); d.y = tag;
  d.z = __float_as_uint(v1); d.w = tag;
  asm volatile("global_store_dwordx4 %0, %1, off sc0 sc1"
               :: "v"(p), "v"(d) : "memory");
}

__device__ __forceinline__ unsigned long long pack_slot(float v, unsigned tag) {
  return ((unsigned long long)tag << 32) | (unsigned long long)__float_as_uint(v);
}

// ---------------------------------------------------------------------------
// Prepass: xproj[t][r] = inputs[t,:]@Wx[r,:] + bx[r] + (r<4M ? bh[r] : bm[r-4M])
// ---------------------------------------------------------------------------
#define GT_K 16
__global__ __launch_bounds__(256) void xproj_gemm(
    const float* __restrict__ A, const float* __restrict__ W,
    const float* __restrict__ bx, const float* __restrict__ bh,
    const float* __restrict__ bm, float* __restrict__ C)
{
  __shared__ float As[GT_K][64 + 4];
  __shared__ float Ws[GT_K][64 + 4];
  const int tid = threadIdx.x;
  const int tx = tid & 15, ty = tid >> 4;
  const int m0 = blockIdx.x * 64;
  const int n0 = blockIdx.y * 64;
  const int lr = tid >> 2;
  const int lk = (tid & 3) * 4;

  float acc[4][4] = {};
  for (int kb = 0; kb < MDIM; kb += GT_K) {
    const float4 av = *(const float4*)(A + (size_t)(m0 + lr) * MDIM + kb + lk);
    const float4 wv = *(const float4*)(W + (size_t)(n0 + lr) * MDIM + kb + lk);
    __syncthreads();
    As[lk + 0][lr] = av.x; As[lk + 1][lr] = av.y;
    As[lk + 2][lr] = av.z; As[lk + 3][lr] = av.w;
    Ws[lk + 0][lr] = wv.x; Ws[lk + 1][lr] = wv.y;
    Ws[lk + 2][lr] = wv.z; Ws[lk + 3][lr] = wv.w;
    __syncthreads();
    #pragma unroll
    for (int kk = 0; kk < GT_K; ++kk) {
      const float4 a = *(const float4*)(&As[kk][ty * 4]);
      const float4 w = *(const float4*)(&Ws[kk][tx * 4]);
      acc[0][0] += a.x * w.x; acc[0][1] += a.x * w.y; acc[0][2] += a.x * w.z; acc[0][3] += a.x * w.w;
      acc[1][0] += a.y * w.x; acc[1][1] += a.y * w.y; acc[1][2] += a.y * w.z; acc[1][3] += a.y * w.w;
      acc[2][0] += a.z * w.x; acc[2][1] += a.z * w.y; acc[2][2] += a.z * w.z; acc[2][3] += a.z * w.w;
      acc[3][0] += a.w * w.x; acc[3][1] += a.w * w.y; acc[3][2] += a.w * w.z; acc[3][3] += a.w * w.w;
    }
  }
  const int rbase = n0 + tx * 4;
  float bias[4];
  #pragma unroll
  for (int q = 0; q < 4; ++q) {
    const int r = rbase + q;
    bias[q] = bx[r] + (r < 4 * MDIM ? bh[r] : bm[r - 4 * MDIM]);
  }
  #pragma unroll
  for (int i = 0; i < 4; ++i) {
    const int row = m0 + ty * 4 + i;
    float4 o;
    o.x = acc[i][0] + bias[0]; o.y = acc[i][1] + bias[1];
    o.z = acc[i][2] + bias[2]; o.w = acc[i][3] + bias[3];
    *(float4*)(C + (size_t)row * NGATE5 + rbase) = o;
  }
}

// ---------------------------------------------------------------------------
// Recurrence R6: 64 WGs x 512 threads (8 waves). Wave w owns columns
// j0=wg*16+2w, j0+1. Contention theory: poll storm (128 WGs x 8 KB/round)
// queues ahead of publisher stores at the ~128 hot LLC lines. Halving WGs
// halves per-line read pressure; packed 16-B dual-slot publish halves store
// requests. Weights: i/o rows in LDS (128 KB), z/f/Wm rows in VGPRs (96).
// Critical path: h arrives -> z-dots (reg weights) -> packed v publish ->
// (i,o,f dots overlap v-wait) -> v arrives -> u-dots -> c,h -> packed publish.
// LDS 136 KB; ~170 VGPR (<=256 @ 2 waves/SIMD).
// ---------------------------------------------------------------------------
__global__ __launch_bounds__(NTHR, 2) void ulstm_persistent_p(
    const float* __restrict__ Wh, const float* __restrict__ Wm,
    const float* __restrict__ xproj, float* __restrict__ out,
    unsigned long long* __restrict__ hslot, unsigned long long* __restrict__ vslot)
{
  __shared__ alignas(16) float sWio[32][MDIM];  // [cl*2 + (0=i,1=o)][k]  128 KB
  __shared__ alignas(16) float hbuf[MDIM];
  __shared__ alignas(16) float vbuf[MDIM];

  const int tid  = threadIdx.x;
  const int wg   = blockIdx.x;
  const int wave = tid >> 6;
  const int lane = tid & 63;
  const int j0   = wg * 16 + wave * 2;     // owned columns j0, j0+1
  const int sb   = tid * 2;                // 2 slots per thread (one dwordx4)

  // ---- one-time staging: i,o gate rows for WG's 16 columns -> LDS ----
  for (int idx = tid; idx < 32 * 256; idx += NTHR) {
    const int r = idx >> 8, k4 = (idx & 255) * 4;
    const int cl = r >> 1, g = r & 1;      // g: 0=i-gate, 1=o-gate
    *(float4*)(&sWio[r][k4]) =
        *(const float4*)(Wh + (size_t)(g * MDIM + wg * 16 + cl) * MDIM + k4);
  }
  // ---- z,f gate rows + Wm rows for both owned columns -> registers ----
  float wz[2][16], wf[2][16], wm[2][16];
  #pragma unroll
  for (int cc = 0; cc < 2; ++cc) {
    #pragma unroll
    for (int i = 0; i < 4; ++i) {
      const int kb = i * 256 + lane * 4;
      const float4 a = *(const float4*)(Wh + (size_t)(2 * MDIM + j0 + cc) * MDIM + kb);
      const float4 b = *(const float4*)(Wh + (size_t)(3 * MDIM + j0 + cc) * MDIM + kb);
      const float4 m = *(const float4*)(Wm + (size_t)(j0 + cc) * MDIM + kb);
      wz[cc][i * 4 + 0] = a.x; wz[cc][i * 4 + 1] = a.y;
      wz[cc][i * 4 + 2] = a.z; wz[cc][i * 4 + 3] = a.w;
      wf[cc][i * 4 + 0] = b.x; wf[cc][i * 4 + 1] = b.y;
      wf[cc][i * 4 + 2] = b.z; wf[cc][i * 4 + 3] = b.w;
      wm[cc][i * 4 + 0] = m.x; wm[cc][i * 4 + 1] = m.y;
      wm[cc][i * 4 + 2] = m.z; wm[cc][i * 4 + 3] = m.w;
    }
  }
  __syncthreads();

  float c0 = 0.f, c1 = 0.f, tc0 = 0.f, tc1 = 0.f, h0 = 0.f, h1 = 0.f;

  for (int t = 0; t < TSTEPS; ++t) {
    // xproj for both columns (issued before the poll; first vmcnt(0) drains)
    const float* xp = xproj + (size_t)t * NGATE5 + j0;
    const float2 xi = *(const float2*)(xp + 0 * MDIM);
    const float2 xo = *(const float2*)(xp + 1 * MDIM);
    const float2 xz = *(const float2*)(xp + 2 * MDIM);
    const float2 xf = *(const float2*)(xp + 3 * MDIM);
    const float2 xu = *(const float2*)(xp + 4 * MDIM);

    // ---- wait for h(t-1): tag==t (memset gives tag0/val0 = h(-1)=0) ----
    {
      u32x4 a;
      for (;;) {
        a = load16_coherent(hslot + sb);
        if (a.y == (unsigned)t && a.w == (unsigned)t) break;
      }
      hbuf[sb + 0] = __uint_as_float(a.x);
      hbuf[sb + 1] = __uint_as_float(a.z);
    }
    __syncthreads();  // S2

    // ---- z-dots (critical path, register weights), packed v publish ----
    float zd0 = 0.f, zd1 = 0.f;
    #pragma unroll
    for (int i = 0; i < 4; ++i) {
      const int kb = i * 256 + lane * 4;
      const float4 hv = *(const float4*)(hbuf + kb);
      zd0 += wz[0][i*4+0]*hv.x + wz[0][i*4+1]*hv.y + wz[0][i*4+2]*hv.z + wz[0][i*4+3]*hv.w;
      zd1 += wz[1][i*4+0]*hv.x + wz[1][i*4+1]*hv.y + wz[1][i*4+2]*hv.z + wz[1][i*4+3]*hv.w;
    }
    #pragma unroll
    for (int off = 32; off > 0; off >>= 1) {
      zd0 += __shfl_xor(zd0, off, 64);
      zd1 += __shfl_xor(zd1, off, 64);
    }
    const float vj0 = sigmoidf_(xz.x + zd0) * tc0;
    const float vj1 = sigmoidf_(xz.y + zd1) * tc1;
    if (lane == 0) store16_coherent(vslot + j0, vj0, vj1, (unsigned)(t + 1));

    // ---- i,o (LDS) + f (regs) dots: overlap the v-exchange ----
    const int rb = wave * 4;
    float id0 = 0.f, od0 = 0.f, id1 = 0.f, od1 = 0.f, fd0 = 0.f, fd1 = 0.f;
    #pragma unroll
    for (int i = 0; i < 4; ++i) {
      const int kb = i * 256 + lane * 4;
      const float4 hv  = *(const float4*)(hbuf + kb);
      const float4 wi0 = *(const float4*)(&sWio[rb + 0][kb]);
      const float4 wo0 = *(const float4*)(&sWio[rb + 1][kb]);
      const float4 wi1 = *(const float4*)(&sWio[rb + 2][kb]);
      const float4 wo1 = *(const float4*)(&sWio[rb + 3][kb]);
      id0 += wi0.x*hv.x + wi0.y*hv.y + wi0.z*hv.z + wi0.w*hv.w;
      od0 += wo0.x*hv.x + wo0.y*hv.y + wo0.z*hv.z + wo0.w*hv.w;
      id1 += wi1.x*hv.x + wi1.y*hv.y + wi1.z*hv.z + wi1.w*hv.w;
      od1 += wo1.x*hv.x + wo1.y*hv.y + wo1.z*hv.z + wo1.w*hv.w;
      fd0 += wf[0][i*4+0]*hv.x + wf[0][i*4+1]*hv.y + wf[0][i*4+2]*hv.z + wf[0][i*4+3]*hv.w;
      fd1 += wf[1][i*4+0]*hv.x + wf[1][i*4+1]*hv.y + wf[1][i*4+2]*hv.z + wf[1][i*4+3]*hv.w;
    }
    #pragma unroll
    for (int off = 32; off > 0; off >>= 1) {
      id0 += __shfl_xor(id0, off, 64);
      od0 += __shfl_xor(od0, off, 64);
      id1 += __shfl_xor(id1, off, 64);
      od1 += __shfl_xor(od1, off, 64);
      fd0 += __shfl_xor(fd0, off, 64);
      fd1 += __shfl_xor(fd1, off, 64);
    }
    const float ig0 = sigmoidf_(xi.x + id0), ig1 = sigmoidf_(xi.y + id1);
    const float og0 = sigmoidf_(xo.x + od0), og1 = sigmoidf_(xo.y + od1);
    const float fg0 = sigmoidf_(xf.x + fd0), fg1 = sigmoidf_(xf.y + fd1);

    // ---- wait for v(t): tag==t+1 ----
    {
      u32x4 a;
      for (;;) {
        a = load16_coherent(vslot + sb);
        if (a.y == (unsigned)(t + 1) && a.w == (unsigned)(t + 1)) break;
      }
      vbuf[sb + 0] = __uint_as_float(a.x);
      vbuf[sb + 1] = __uint_as_float(a.z);
    }
    __syncthreads();  // S3

    // ---- u-dots from registers ----
    float md0 = 0.f, md1 = 0.f;
    #pragma unroll
    for (int i = 0; i < 4; ++i) {
      const int kb = i * 256 + lane * 4;
      const float4 vv = *(const float4*)(vbuf + kb);
      md0 += wm[0][i*4+0]*vv.x + wm[0][i*4+1]*vv.y + wm[0][i*4+2]*vv.z + wm[0][i*4+3]*vv.w;
      md1 += wm[1][i*4+0]*vv.x + wm[1][i*4+1]*vv.y + wm[1][i*4+2]*vv.z + wm[1][i*4+3]*vv.w;
    }
    #pragma unroll
    for (int off = 32; off > 0; off >>= 1) {
      md0 += __shfl_xor(md0, off, 64);
      md1 += __shfl_xor(md1, off, 64);
    }
    const float u0 = tanhf_(xu.x + md0);
    const float u1 = tanhf_(xu.y + md1);
    c0 = ig0 * u0 + fg0 * c0;
    c1 = ig1 * u1 + fg1 * c1;
    const float t0n = tanhf_(c0);
    const float t1n = tanhf_(c1);
    h0 = og0 * t0n;
    h1 = og1 * t1n;
    if (lane == 0) store16_coherent(hslot + j0, h0, h1, (unsigned)(t + 1));
    tc0 = t0n; tc1 = t1n;
  }

  if (lane == 0) {
    out[j0] = c0;        out[j0 + 1] = c1;
    out[MDIM + j0] = h0; out[MDIM + j0 + 1] = h1;
  }
}

// ---------------------------------------------------------------------------
// Fallback (ws too small for xproj): 256 WGs x 256 thr, weights from cache,
// 4 slots/thread fused-wait poll.
// ---------------------------------------------------------------------------
__device__ __forceinline__ void poll4(const unsigned long long* __restrict__ slots,
                                      float* __restrict__ dst, int base, unsigned want) {
  u32x4 a, b;
  for (;;) {
    asm volatile("global_load_dwordx4 %0, %2, off sc0 sc1\n\t"
                 "global_load_dwordx4 %1, %3, off sc0 sc1\n\t"
                 "s_waitcnt vmcnt(0)"
                 : "=&v"(a), "=&v"(b)
                 : "v"(slots + base), "v"(slots + base + 2) : "memory");
    if (a.y == want && a.w == want && b.y == want && b.w == want) break;
  }
  dst[base + 0] = __uint_as_float(a.x);
  dst[base + 1] = __uint_as_float(a.z);
  dst[base + 2] = __uint_as_float(b.x);
  dst[base + 3] = __uint_as_float(b.z);
}

__global__ __launch_bounds__(256, 1) void ulstm_persistent_f(
    const float* __restrict__ inputs, const float* __restrict__ Wx,
    const float* __restrict__ bx, const float* __restrict__ Wh,
    const float* __restrict__ bh, const float* __restrict__ Wm,
    const float* __restrict__ bm, float* __restrict__ out,
    unsigned long long* __restrict__ hslot, unsigned long long* __restrict__ vslot)
{
  __shared__ alignas(16) float xbuf[MDIM];
  __shared__ alignas(16) float hbuf[MDIM];
  __shared__ alignas(16) float vbuf[MDIM];

  const int tid  = threadIdx.x;
  const int wg   = blockIdx.x;
  const int wave = tid >> 6;
  const int lane = tid & 63;
  const int j    = wg * 4 + wave;
  const int slotbase = tid * 4;

  const float bxi = bx[j],            bxo = bx[MDIM + j],
              bxz = bx[2 * MDIM + j], bxf = bx[3 * MDIM + j],
              bxu = bx[4 * MDIM + j];
  const float bhi = bh[j],            bho = bh[MDIM + j],
              bhz = bh[2 * MDIM + j], bhf = bh[3 * MDIM + j];
  const float bmj = bm[j];

  float c = 0.f, hlast = 0.f;

  for (int t = 0; t < TSTEPS; ++t) {
    {
      float4 v = ((const float4*)(inputs + (size_t)t * MDIM))[tid];
      ((float4*)xbuf)[tid] = v;
    }
    __syncthreads();

    float xd[5] = {0, 0, 0, 0, 0};
    #pragma unroll
    for (int i = 0; i < 4; ++i) {
      const int kb = i * 256 + lane * 4;
      const float4 xv = *(const float4*)(xbuf + kb);
      #pragma unroll
      for (int g = 0; g < 5; ++g) {
        const float4 w = *(const float4*)(Wx + ((size_t)(g * MDIM + j)) * MDIM + kb);
        xd[g] += w.x * xv.x + w.y * xv.y + w.z * xv.z + w.w * xv.w;
      }
    }
    #pragma unroll
    for (int off = 32; off > 0; off >>= 1)
      #pragma unroll
      for (int g = 0; g < 5; ++g) xd[g] += __shfl_xor(xd[g], off, 64);

    poll4(hslot, hbuf, slotbase, (unsigned)t);
    __syncthreads();

    float hd[4] = {0, 0, 0, 0};
    #pragma unroll
    for (int i = 0; i < 4; ++i) {
      const int kb = i * 256 + lane * 4;
      const float4 hv = *(const float4*)(hbuf + kb);
      #pragma unroll
      for (int g = 0; g < 4; ++g) {
        const float4 w = *(const float4*)(Wh + ((size_t)(g * MDIM + j)) * MDIM + kb);
        hd[g] += w.x * hv.x + w.y * hv.y + w.z * hv.z + w.w * hv.w;
      }
    }
    #pragma unroll
    for (int off = 32; off > 0; off >>= 1)
      #pragma unroll
      for (int g = 0; g < 4; ++g) hd[g] += __shfl_xor(hd[g], off, 64);

    const float ig = sigmoidf_(xd[0] + bxi + hd[0] + bhi);
    const float og = sigmoidf_(xd[1] + bxo + hd[1] + bho);
    const float zg = sigmoidf_(xd[2] + bxz + hd[2] + bhz);
    const float fg = sigmoidf_(xd[3] + bxf + hd[3] + bhf);
    const float vj = zg * tanhf_(c);
    if (lane == 0)
      __hip_atomic_store(vslot + j, pack_slot(vj, (unsigned)(t + 1)),
                         __ATOMIC_RELAXED, __HIP_MEMORY_SCOPE_AGENT);

    poll4(vslot, vbuf, slotbase, (unsigned)(t + 1));
    __syncthreads();

    float md = 0;
    #pragma unroll
    for (int i = 0; i < 4; ++i) {
      const int kb = i * 256 + lane * 4;
      const float4 vv = *(const float4*)(vbuf + kb);
      const float4 w = *(const float4*)(Wm + (size_t)j * MDIM + kb);
      md += w.x * vv.x + w.y * vv.y + w.z * vv.z + w.w * vv.w;
    }
    #pragma unroll
    for (int off = 32; off > 0; off >>= 1) md += __shfl_xor(md, off, 64);

    const float u = tanhf_(xd[4] + bxu + md + bmj);
    c = ig * u + fg * c;
    hlast = og * tanhf_(c);
    if (lane == 0)
      __hip_atomic_store(hslot + j, pack_slot(hlast, (unsigned)(t + 1)),
                         __ATOMIC_RELAXED, __HIP_MEMORY_SCOPE_AGENT);
  }

  if (lane == 0) {
    out[j] = c;
    out[MDIM + j] = hlast;
  }
}

extern "C" void kernel_launch(void* const* d_in, const int* in_sizes, int n_in,
                              void* d_out, int out_size, void* d_ws, size_t ws_size,
                              hipStream_t stream) {
  const float* inputs = (const float*)d_in[0];
  const float* Wx     = (const float*)d_in[1];
  const float* bx     = (const float*)d_in[2];
  const float* Wh     = (const float*)d_in[3];
  const float* bh     = (const float*)d_in[4];
  const float* Wm     = (const float*)d_in[5];
  const float* bm     = (const float*)d_in[6];
  float* out = (float*)d_out;

  unsigned long long* hslot = (unsigned long long*)d_ws;
  unsigned long long* vslot = hslot + MDIM;
  const size_t slot_bytes = 2 * MDIM * sizeof(unsigned long long);
  const size_t xp_bytes   = (size_t)TSTEPS * NGATE5 * sizeof(float);

  hipMemsetAsync(d_ws, 0, slot_bytes, stream);

  if (ws_size >= slot_bytes + xp_bytes) {
    float* xproj = (float*)((char*)d_ws + slot_bytes);
    xproj_gemm<<<dim3(TSTEPS / 64, NGATE5 / 64), 256, 0, stream>>>(
        inputs, Wx, bx, bh, bm, xproj);
    ulstm_persistent_p<<<NWG, NTHR, 0, stream>>>(Wh, Wm, xproj, out, hslot, vslot);
  } else {
    ulstm_persistent_f<<<256, 256, 0, stream>>>(inputs, Wx, bx, Wh, bh, Wm, bm,
                                                out, hslot, vslot);
  }
}